// Round 6
// baseline (710.409 us; speedup 1.0000x reference)
//
#include <hip/hip_runtime.h>

// ---------------------------------------------------------------------------
// Swin block, MI355X bf16-MFMA implementation.
// Shapes: B=32, H=W=56, DIM=256, WS=7, SHIFT=3, NH=8, HD=32, N=49, nW=64,
// Bw=2048, tokens T=100352.
// R1: attn_proj: comb bias table + LDS XOR-swizzles (landed)
// R2: gemm_bt 128²: dbuf prefetch + XCD-chunked grid (landed: 678 µs)
// R3/R5: counted-vmcnt pipelining on the 128² 2-phase structure (NULL both
//     ways -> m233 regime: stage+wait+barrier IS the critical path there)
// R4: mlp_fused (REGRESSED; reverted)
// R6: gemm256 — the 8-phase-style structure the counted-vmcnt needs:
//     256² tile, 512 thr / 8 waves (2Mx4N, 128x64 per wave), BK=32,
//     4-deep LDS ring (128KB dynamic, 1 block/CU), per K-step two phases
//     {stage A(t+3) | ds_read A0-3,B0-3 | bar | setprio MFMAx16 | bar}
//     {stage B(t+3) | ds_read A4-7     | bar | setprio MFMAx16 | vmcnt(8) | bar}
//     vmcnt never drains to 0 mid-loop (T3+T4+T5 combo, m201 lineage).
// ---------------------------------------------------------------------------

typedef float f4 __attribute__((ext_vector_type(4)));
typedef __bf16 b8 __attribute__((ext_vector_type(8)));

#define DEV static __device__ __forceinline__

DEV ushort f2bf(float f) {
  union { float f; unsigned u; } c; c.f = f;
  unsigned u = c.u;
  u += 0x7fffu + ((u >> 16) & 1u);   // RNE
  return (ushort)(u >> 16);
}
DEV __bf16 bfb(ushort u) { union { ushort u; __bf16 b; } c; c.u = u; return c.b; }
DEV b8 zero_b8() {
  b8 z;
#pragma unroll
  for (int i = 0; i < 8; ++i) z[i] = (__bf16)0.f;
  return z;
}
DEV void load_lds16(const void* g, void* l) {
  // lane i's 16B land at ldsbase + i*16 (wave-uniform base) [m97/m104]
  __builtin_amdgcn_global_load_lds(
      (const __attribute__((address_space(1))) unsigned int*)g,
      (__attribute__((address_space(3))) unsigned int*)l, 16, 0, 0);
}
DEV int reg3(int t) { return t < 49 ? 0 : (t < 53 ? 1 : 2); }  // shift-mask region row/col id

// ---------------------------------------------------------------------------
// weights fp32 -> bf16
__global__ __launch_bounds__(256) void cast_w(const float* a, ushort* oa, int na,
                                              const float* b, ushort* ob, int nb,
                                              const float* c, ushort* oc, int nc,
                                              const float* d, ushort* od, int nd) {
  int total = na + nb + nc + nd;
  for (int i = blockIdx.x * 256 + threadIdx.x; i < total; i += gridDim.x * 256) {
    int j = i;
    if (j < na) { oa[j] = f2bf(a[j]); continue; }
    j -= na;
    if (j < nb) { ob[j] = f2bf(b[j]); continue; }
    j -= nb;
    if (j < nc) { oc[j] = f2bf(c[j]); continue; }
    j -= nc;
    od[j] = f2bf(d[j]);
  }
}

// ---------------------------------------------------------------------------
// comb[type][h][i][j]: rel-pos bias + shift mask + pad (-1e30), fp32.
// type = (wh==7)*2 + (ww==7) — only 4 distinct window mask patterns exist.
__global__ __launch_bounds__(256) void build_bias(const float* __restrict__ rel_table,
                                                  float* __restrict__ comb) {
  const int idx = blockIdx.x * 256 + threadIdx.x;  // 4*8*64*64 = 131072
  if (idx >= 4 * 8 * 64 * 64) return;
  const int j = idx & 63, i = (idx >> 6) & 63, h = (idx >> 12) & 7, ty = idx >> 15;
  float v;
  if (i < 49 && j < 49) {
    const int iy = i / 7, ix = i - iy * 7, jy = j / 7, jx = j - jy * 7;
    const int ridx = (iy - jy + 6) * 13 + (ix - jx + 6);
    v = rel_table[ridx * 8 + h];
    const int wh = (ty & 2) ? 7 : 0, ww = (ty & 1) ? 7 : 0;
    const int irg = reg3(wh * 7 + iy) * 3 + reg3(ww * 7 + ix);
    const int jrg = reg3(wh * 7 + jy) * 3 + reg3(ww * 7 + jx);
    if (irg != jrg) v -= 100.f;
  } else {
    v = -1e30f;  // padding: exp(-inf) = 0 for j>=49; rows i>=49 harmless
  }
  comb[idx] = v;
}

// ---------------------------------------------------------------------------
// LayerNorm over 256 ch, one wave per token; optional (-3,-3) cyclic shift +
// window partition on the output index. out: bf16 (token, 256) row-major.
__global__ __launch_bounds__(256) void ln_shift(const float* __restrict__ x,
                                                const float* __restrict__ g,
                                                const float* __restrict__ bta,
                                                ushort* __restrict__ out, int shifted) {
  const int wid = threadIdx.x >> 6, lane = threadIdx.x & 63;
  const int t = blockIdx.x * 4 + wid;           // output token (windowed order if shifted)
  int src;
  if (shifted) {
    int win = t / 49, n = t - win * 49;
    int bb = win >> 6, wh = (win >> 3) & 7, ww = win & 7;
    int wy = n / 7, wx = n - wy * 7;
    int r = wh * 7 + wy + 3; if (r >= 56) r -= 56;
    int c = ww * 7 + wx + 3; if (c >= 56) c -= 56;
    src = bb * 3136 + r * 56 + c;
  } else {
    src = t;
  }
  const float4 v = *(const float4*)(x + (size_t)src * 256 + lane * 4);
  float s  = v.x + v.y + v.z + v.w;
  float s2 = v.x * v.x + v.y * v.y + v.z * v.z + v.w * v.w;
#pragma unroll
  for (int m = 32; m; m >>= 1) { s += __shfl_xor(s, m); s2 += __shfl_xor(s2, m); }
  const float mean = s * (1.f / 256.f);
  const float var  = s2 * (1.f / 256.f) - mean * mean;
  const float rs   = rsqrtf(var + 1e-5f);
  const float4 gv = *(const float4*)(g + lane * 4);
  const float4 bv = *(const float4*)(bta + lane * 4);
  ushort4 o;
  o.x = f2bf((v.x - mean) * rs * gv.x + bv.x);
  o.y = f2bf((v.y - mean) * rs * gv.y + bv.y);
  o.z = f2bf((v.z - mean) * rs * gv.z + bv.z);
  o.w = f2bf((v.w - mean) * rs * gv.w + bv.w);
  *(ushort4*)(out + (size_t)t * 256 + lane * 4) = o;
}

// ---------------------------------------------------------------------------
// 256x256-tile bf16 GEMM: C[M,N] = A[M,K] @ B[N,K]^T, BK=32, 512 thr
// (8 waves: wm=wid>>2 in {0,1} rows, wn=wid&3 cols; 128x64 C per wave).
// 4-deep LDS ring (dynamic 128KB, 1 block/CU). Per K-step, 2 phases:
//   a: stage A(t+3); ds_read A ti0-3 + B tj0-3; bar; setprio MFMAx16; bar
//   b: stage B(t+3); ds_read A ti4-7;           bar; setprio MFMAx16;
//      s_waitcnt vmcnt(8) [tile t+1 landed; 2 future steps stay in flight];
//      bar
// Safety: stage(t+3) overwrites buf[(t-1)&3] (reads done before the step
// t-1 final barrier); 4 gload_lds per wave per K-step -> vmcnt(8) retires
// exactly tile t+1; tail peels 8->4->0; all branches block-uniform.
// Requires nsteps >= 3 (K >= 96). Grid: 8*49*NT, XCD-chunked remap.
template <class Epi>
__global__ __launch_bounds__(512, 2) void gemm256(const ushort* __restrict__ A,
                                                  const ushort* __restrict__ B,
                                                  int K, int NT, Epi epi) {
  extern __shared__ __align__(16) ushort smem[];   // [4][256*32] A ; [4][256*32] B
  ushort* lsA = smem;
  ushort* lsB = smem + 4 * 8192;
  const int tid = threadIdx.x;
  const int lane = tid & 63, wid = tid >> 6;
  const int quad = lane >> 4, l16 = lane & 15;
  const int wm = wid >> 2, wn = wid & 3;
  // XCD-chunked bijective remap (nwg = 392*NT = 8*49*NT)
  const int lin = blockIdx.x;
  const int xcd = lin & 7, jj = lin >> 3;
  const int mt = xcd * 49 + jj / NT;
  const int nt_ = jj % NT;
  const long rowA0 = (long)mt * 256;
  const long colB0 = (long)nt_ * 256;
  f4 acc[8][4];
#pragma unroll
  for (int i = 0; i < 8; ++i)
#pragma unroll
    for (int j = 0; j < 4; ++j) { acc[i][j][0] = 0.f; acc[i][j][1] = 0.f; acc[i][j][2] = 0.f; acc[i][j][3] = 0.f; }
  const int lrow = lane >> 2;
  const int lk = ((lane & 3) ^ ((lane >> 3) & 3)) * 8;   // swizzled global k-chunk
  const int rsw = (quad ^ ((l16 >> 1) & 3)) * 8;         // swizzled read slot
  const int seg0 = wid * 2, seg1 = wid * 2 + 1;          // wave-uniform segments (0..15)
  const long ga0 = (rowA0 + seg0 * 16 + lrow) * (long)K + lk;
  const long ga1 = (rowA0 + seg1 * 16 + lrow) * (long)K + lk;
  const long gb0 = (colB0 + seg0 * 16 + lrow) * (long)K + lk;
  const long gb1 = (colB0 + seg1 * 16 + lrow) * (long)K + lk;

  const int nsteps = K >> 5;
  // prologue: stage tiles 0,1,2 (12 loads/wave outstanding)
#pragma unroll
  for (int p = 0; p < 3; ++p) {
    const int bo = p * 8192, kk = p << 5;
    load_lds16(A + ga0 + kk, lsA + bo + seg0 * 512);
    load_lds16(A + ga1 + kk, lsA + bo + seg1 * 512);
    load_lds16(B + gb0 + kk, lsB + bo + seg0 * 512);
    load_lds16(B + gb1 + kk, lsB + bo + seg1 * 512);
  }
  asm volatile("s_waitcnt vmcnt(8)" ::: "memory");   // tile 0 landed
  __builtin_amdgcn_s_barrier();

  for (int t = 0; t < nsteps; ++t) {
    const ushort* bufA = lsA + (t & 3) * 8192;
    const ushort* bufB = lsB + (t & 3) * 8192;
    const int sbo = ((t + 3) & 3) * 8192, skk = (t + 3) << 5;
    // ---- phase a: stage A(t+3); read A0-3 + B0-3; 16 MFMA
    if (t + 3 < nsteps) {
      load_lds16(A + ga0 + skk, lsA + sbo + seg0 * 512);
      load_lds16(A + ga1 + skk, lsA + sbo + seg1 * 512);
    }
    b8 af[4], bfr[4];
#pragma unroll
    for (int ti = 0; ti < 4; ++ti)
      af[ti] = *(const b8*)&bufA[(wm * 128 + ti * 16 + l16) * 32 + rsw];
#pragma unroll
    for (int tj = 0; tj < 4; ++tj)
      bfr[tj] = *(const b8*)&bufB[(wn * 64 + tj * 16 + l16) * 32 + rsw];
    __builtin_amdgcn_s_barrier();
    __builtin_amdgcn_s_setprio(1);
#pragma unroll
    for (int ti = 0; ti < 4; ++ti)
#pragma unroll
      for (int tj = 0; tj < 4; ++tj)
        acc[ti][tj] = __builtin_amdgcn_mfma_f32_16x16x32_bf16(af[ti], bfr[tj], acc[ti][tj], 0, 0, 0);
    __builtin_amdgcn_s_setprio(0);
    __builtin_amdgcn_s_barrier();
    // ---- phase b: stage B(t+3); read A4-7; 16 MFMA; counted wait
    if (t + 3 < nsteps) {
      load_lds16(B + gb0 + skk, lsB + sbo + seg0 * 512);
      load_lds16(B + gb1 + skk, lsB + sbo + seg1 * 512);
    }
    b8 af2[4];
#pragma unroll
    for (int ti = 0; ti < 4; ++ti)
      af2[ti] = *(const b8*)&bufA[(wm * 128 + (4 + ti) * 16 + l16) * 32 + rsw];
    __builtin_amdgcn_s_barrier();
    __builtin_amdgcn_s_setprio(1);
#pragma unroll
    for (int ti = 0; ti < 4; ++ti)
#pragma unroll
      for (int tj = 0; tj < 4; ++tj)
        acc[4 + ti][tj] = __builtin_amdgcn_mfma_f32_16x16x32_bf16(af2[ti], bfr[tj], acc[4 + ti][tj], 0, 0, 0);
    __builtin_amdgcn_s_setprio(0);
    if (t + 3 < nsteps) {
      asm volatile("s_waitcnt vmcnt(8)" ::: "memory");  // tile t+1 landed
    } else if (t + 2 < nsteps) {
      asm volatile("s_waitcnt vmcnt(4)" ::: "memory");
    } else if (t + 1 < nsteps) {
      asm volatile("s_waitcnt vmcnt(0)" ::: "memory");
    }
    __builtin_amdgcn_s_barrier();   // publish tile t+1; all reads of t done
  }
  // C/D layout: row = quad*4+reg, col = lane&15 [m89/m91]
#pragma unroll
  for (int ti = 0; ti < 8; ++ti)
#pragma unroll
    for (int tj = 0; tj < 4; ++tj)
#pragma unroll
      for (int r = 0; r < 4; ++r)
        epi((int)(rowA0 + wm * 128 + ti * 16 + quad * 4 + r),
            (int)(colB0 + wn * 64 + tj * 16 + l16), acc[ti][tj][r]);
}

struct QkvEpi {
  ushort* out; const float* bias;
  __device__ void operator()(int r, int c, float v) const {
    v += bias[c];
    if (c < 256) v *= 0.17677669529663687f;  // HD^-0.5, pre-scale q
    out[(size_t)r * 768 + c] = f2bf(v);
  }
};
struct GeluEpi {
  ushort* out; const float* bias;
  __device__ void operator()(int r, int c, float v) const {
    v += bias[c];
    v = 0.5f * v * (1.f + erff(v * 0.70710678118654752f));  // exact gelu
    out[(size_t)r * 1024 + c] = f2bf(v);
  }
};
struct Fc2Epi {
  float* out; const float* bias;
  __device__ void operator()(int r, int c, float v) const {
    size_t i = (size_t)r * 256 + c;
    out[i] = out[i] + v + bias[c];  // += y onto x_after already in d_out
  }
};

// ---------------------------------------------------------------------------
// Attention + proj + residual + LN2, one block per window (512 thr), one
// wave/head. qkv rows: [q(256, pre-scaled) | k(256) | v(256)] bf16.
// Writes x_after (fp32, d_out) and LN2(x_after) (bf16, fc1's A) directly.
__global__ __launch_bounds__(512) void attn_proj(const ushort* __restrict__ qkv,
                                                 const float* __restrict__ comb,
                                                 const ushort* __restrict__ projw,
                                                 const float* __restrict__ projb,
                                                 const float* __restrict__ x_in,
                                                 const float* __restrict__ n2g,
                                                 const float* __restrict__ n2b,
                                                 float* __restrict__ x_out,
                                                 ushort* __restrict__ xw2) {
  __shared__ ushort sbuf[32768];  // 64KB: P (8 x 64x64) ; O staging ; fp32 x_after
  const int win = blockIdx.x;
  const int b = win >> 6, wh = (win >> 3) & 7, ww = win & 7;
  const int tid = threadIdx.x, lane = tid & 63, h = tid >> 6;
  const int quad = lane >> 4, l16 = lane & 15;
  const size_t wbase = (size_t)win * 49 * 768;

  // ---- Phase 1: S = (q*scale) @ k^T, padded to 64x64, K=32 (one MFMA/tile)
  b8 af[4], bfr[4];
#pragma unroll
  for (int ti = 0; ti < 4; ++ti) {
    const int tok = ti * 16 + l16;
    af[ti] = (tok < 49) ? *(const b8*)(qkv + wbase + (size_t)tok * 768 + h * 32 + quad * 8)
                        : zero_b8();
  }
#pragma unroll
  for (int tj = 0; tj < 4; ++tj) {
    const int key = tj * 16 + l16;
    bfr[tj] = (key < 49) ? *(const b8*)(qkv + wbase + (size_t)key * 768 + 256 + h * 32 + quad * 8)
                         : zero_b8();
  }
  f4 S[4][4];
#pragma unroll
  for (int ti = 0; ti < 4; ++ti)
#pragma unroll
    for (int tj = 0; tj < 4; ++tj) {
      S[ti][tj][0] = 0.f; S[ti][tj][1] = 0.f; S[ti][tj][2] = 0.f; S[ti][tj][3] = 0.f;
      S[ti][tj] = __builtin_amdgcn_mfma_f32_16x16x32_bf16(af[ti], bfr[tj], S[ti][tj], 0, 0, 0);
    }

  // ---- Phase 2: + precombined bias/mask table (coalesced L2 reads), row
  // softmax, P -> LDS bf16 with 16B-chunk XOR swizzle (chunk ^= row&7).
  ushort* P = sbuf + h * 4096;  // this head's 64x64
  const float* cmb = comb + ((((wh == 7) ? 2 : 0) + ((ww == 7) ? 1 : 0)) * 8 + h) * 4096;
#pragma unroll
  for (int ti = 0; ti < 4; ++ti) {
#pragma unroll
    for (int r = 0; r < 4; ++r) {
      const int i = ti * 16 + quad * 4 + r;
      const float* crow = cmb + i * 64 + l16;
      float sv[4];
#pragma unroll
      for (int tj = 0; tj < 4; ++tj) sv[tj] = S[ti][tj][r] + crow[tj * 16];
      float m = fmaxf(fmaxf(sv[0], sv[1]), fmaxf(sv[2], sv[3]));
#pragma unroll
      for (int d = 1; d < 16; d <<= 1) m = fmaxf(m, __shfl_xor(m, d));
      float sum = 0.f;
#pragma unroll
      for (int tj = 0; tj < 4; ++tj) { sv[tj] = __expf(sv[tj] - m); sum += sv[tj]; }
#pragma unroll
      for (int d = 1; d < 16; d <<= 1) sum += __shfl_xor(sum, d);
      const float inv = 1.f / sum;
      const int swz = i & 7, off = l16 & 7, cb = l16 >> 3;
#pragma unroll
      for (int tj = 0; tj < 4; ++tj) {
        const int cc = tj * 2 + cb;
        P[i * 64 + (((cc ^ swz) << 3) | off)] = f2bf(sv[tj] * inv);
      }
    }
  }

  // ---- Phase 3: O = P @ V (K=64 keys, 2 MFMAs per 16x16 out tile)
  f4 O[4][2];
#pragma unroll
  for (int ti = 0; ti < 4; ++ti)
#pragma unroll
    for (int tn = 0; tn < 2; ++tn) { O[ti][tn][0] = 0.f; O[ti][tn][1] = 0.f; O[ti][tn][2] = 0.f; O[ti][tn][3] = 0.f; }
#pragma unroll
  for (int kt = 0; kt < 2; ++kt) {
    b8 vb[2];
#pragma unroll
    for (int tn = 0; tn < 2; ++tn)
#pragma unroll
      for (int j = 0; j < 8; ++j) {
        const int key = kt * 32 + quad * 8 + j;  // B-frag: b[j]=V[k=quad*8+j][n=lane&15]
        vb[tn][j] = (key < 49)
            ? bfb(qkv[wbase + (size_t)key * 768 + 512 + h * 32 + tn * 16 + l16])
            : (__bf16)0.f;
      }
#pragma unroll
    for (int ti = 0; ti < 4; ++ti) {
      const int row = ti * 16 + l16;
      const b8 pa = *(const b8*)(P + row * 64 + (((kt * 4 + quad) ^ (row & 7)) << 3));
#pragma unroll
      for (int tn = 0; tn < 2; ++tn)
        O[ti][tn] = __builtin_amdgcn_mfma_f32_16x16x32_bf16(pa, vb[tn], O[ti][tn], 0, 0, 0);
    }
  }

  // ---- Phase 4: stage O (64 x 256 bf16) in LDS, XOR-swizzled (aliases P)
  __syncthreads();
  ushort* ob = sbuf;
#pragma unroll
  for (int ti = 0; ti < 4; ++ti)
#pragma unroll
    for (int tn = 0; tn < 2; ++tn)
#pragma unroll
      for (int r = 0; r < 4; ++r) {
        const int tok = ti * 16 + quad * 4 + r;
        const int cc = h * 4 + tn * 2 + (l16 >> 3);
        ob[tok * 256 + (((cc ^ (tok & 7)) << 3) | (l16 & 7))] = f2bf(O[ti][tn][r]);
      }
  __syncthreads();

  // ---- Phase 5: proj: (64x256) @ projw(256,256)^T; wave h owns 32 out cols
  f4 C[4][2];
#pragma unroll
  for (int ti = 0; ti < 4; ++ti)
#pragma unroll
    for (int tn = 0; tn < 2; ++tn) { C[ti][tn][0] = 0.f; C[ti][tn][1] = 0.f; C[ti][tn][2] = 0.f; C[ti][tn][3] = 0.f; }
  for (int k0 = 0; k0 < 256; k0 += 32) {
    b8 bw[2];
#pragma unroll
    for (int tn = 0; tn < 2; ++tn)
      bw[tn] = *(const b8*)(projw + (size_t)(h * 32 + tn * 16 + l16) * 256 + k0 + quad * 8);
#pragma unroll
    for (int ti = 0; ti < 4; ++ti) {
      const int row = ti * 16 + l16;
      const b8 pa = *(const b8*)(ob + row * 256 + ((((k0 >> 3) + quad) ^ (row & 7)) << 3));
#pragma unroll
      for (int tn = 0; tn < 2; ++tn)
        C[ti][tn] = __builtin_amdgcn_mfma_f32_16x16x32_bf16(pa, bw[tn], C[ti][tn], 0, 0, 0);
    }
  }

  // ---- Phase 6: stage proj output (64x256 fp32, 64KB) in LDS, float4-chunk
  // XOR swizzle (chunk ^= tok&7) to spread write banks.
  __syncthreads();  // all waves done reading ob
  float* fbuf = (float*)sbuf;
#pragma unroll
  for (int ti = 0; ti < 4; ++ti)
#pragma unroll
    for (int r = 0; r < 4; ++r) {
      const int tok = ti * 16 + quad * 4 + r;
      const int swz = tok & 7;
#pragma unroll
      for (int tn = 0; tn < 2; ++tn) {
        const int c4 = h * 8 + tn * 4 + (l16 >> 2);
        fbuf[tok * 256 + (((c4 ^ swz) << 2) | (l16 & 3))] = C[ti][tn][r];
      }
    }
  __syncthreads();

  // ---- Phase 7: per-token: x_after = proj + projb + shortcut (inverse
  // shift), store fp32; fused LN2 -> bf16 xw2 (raster token order).
  for (int t = h; t < 49; t += 8) {
    const int wy = t / 7, wx = t - wy * 7;
    int rr = wh * 7 + wy + 3; if (rr >= 56) rr -= 56;
    int cc = ww * 7 + wx + 3; if (cc >= 56) cc -= 56;
    const size_t base = ((size_t)b * 3136 + rr * 56 + cc) * 256;
    // swizzled read: location chunk lane^(t&7) holds column chunk `lane`
    float4 v = *(float4*)&fbuf[t * 256 + ((lane ^ (t & 7)) << 2)];
    const float4 pb = *(const float4*)(projb + lane * 4);
    const float4 xr = *(const float4*)(x_in + base + lane * 4);
    v.x += pb.x + xr.x; v.y += pb.y + xr.y; v.z += pb.z + xr.z; v.w += pb.w + xr.w;
    *(float4*)(x_out + base + lane * 4) = v;
    float s  = v.x + v.y + v.z + v.w;
    float s2 = v.x * v.x + v.y * v.y + v.z * v.z + v.w * v.w;
#pragma unroll
    for (int m = 32; m; m >>= 1) { s += __shfl_xor(s, m); s2 += __shfl_xor(s2, m); }
    const float mean = s * (1.f / 256.f);
    const float var  = s2 * (1.f / 256.f) - mean * mean;
    const float rs   = rsqrtf(var + 1e-5f);
    const float4 gv = *(const float4*)(n2g + lane * 4);
    const float4 bv = *(const float4*)(n2b + lane * 4);
    ushort4 o;
    o.x = f2bf((v.x - mean) * rs * gv.x + bv.x);
    o.y = f2bf((v.y - mean) * rs * gv.y + bv.y);
    o.z = f2bf((v.z - mean) * rs * gv.z + bv.z);
    o.w = f2bf((v.w - mean) * rs * gv.w + bv.w);
    *(ushort4*)(xw2 + base + lane * 4) = o;
  }
}

// ---------------------------------------------------------------------------
extern "C" void kernel_launch(void* const* d_in, const int* in_sizes, int n_in,
                              void* d_out, int out_size, void* d_ws, size_t ws_size,
                              hipStream_t stream) {
  const float* x     = (const float*)d_in[0];
  const float* n1g   = (const float*)d_in[1];
  const float* n1b   = (const float*)d_in[2];
  const float* qkvw  = (const float*)d_in[3];
  const float* qkvb  = (const float*)d_in[4];
  const float* relt  = (const float*)d_in[5];
  const float* projw = (const float*)d_in[6];
  const float* projb = (const float*)d_in[7];
  const float* n2g   = (const float*)d_in[8];
  const float* n2b   = (const float*)d_in[9];
  const float* fc1w  = (const float*)d_in[10];
  const float* fc1b  = (const float*)d_in[11];
  const float* fc2w  = (const float*)d_in[12];
  const float* fc2b  = (const float*)d_in[13];
  float* out = (float*)d_out;
  char* ws = (char*)d_ws;

  // ws layout:
  //   [0, 51.4MB)        xw: LN1 windowed bf16 A; reused as LN2 output (xw2)
  //   [51.4, 256.9MB)    qkv bf16 (154.1MB); reused as fc1 hidden (205.5MB)
  //   [205.5, 206.0MB)   comb bias/mask table (512KB) — dead space until fc1
  //                      overwrites it (attn_proj has finished by then)
  //   [256.9, 258.5MB)   bf16 weights
  ushort* xw     = (ushort*)ws;
  ushort* qkv    = (ushort*)(ws + 51380224);
  ushort* hidden = qkv;
  float*  comb   = (float*)(ws + 205520896);   // after qkv's 154,140,672 bytes
  ushort* wqkv   = (ushort*)(ws + 51380224 + 205520896);
  ushort* wproj  = wqkv + 196608;
  ushort* wfc1   = wproj + 65536;
  ushort* wfc2   = wfc1 + 262144;

  static bool attr_done = false;
  if (!attr_done) {
    attr_done = true;
    hipFuncSetAttribute(reinterpret_cast<const void*>(&gemm256<QkvEpi>),
                        hipFuncAttributeMaxDynamicSharedMemorySize, 131072);
    hipFuncSetAttribute(reinterpret_cast<const void*>(&gemm256<GeluEpi>),
                        hipFuncAttributeMaxDynamicSharedMemorySize, 131072);
    hipFuncSetAttribute(reinterpret_cast<const void*>(&gemm256<Fc2Epi>),
                        hipFuncAttributeMaxDynamicSharedMemorySize, 131072);
  }

  cast_w<<<768, 256, 0, stream>>>(qkvw, wqkv, 196608, projw, wproj, 65536,
                                  fc1w, wfc1, 262144, fc2w, wfc2, 262144);
  build_bias<<<512, 256, 0, stream>>>(relt, comb);
  // LN1 + shift + window partition -> bf16
  ln_shift<<<25088, 256, 0, stream>>>(x, n1g, n1b, xw, 1);
  // qkv: (100352,256) @ (768,256)^T — 256² tiles, NT=3, grid 8*49*3
  gemm256<<<1176, 512, 131072, stream>>>(xw, wqkv, 256, 3, QkvEpi{qkv, qkvb});
  // attention + proj + residual + inverse shift + LN2 -> d_out, xw (bf16)
  attn_proj<<<2048, 512, 0, stream>>>(qkv, comb, wproj, projb, x, n2g, n2b, out, xw);
  // fc1 + gelu: (100352,256) @ (1024,256)^T — NT=4
  gemm256<<<1568, 512, 131072, stream>>>(xw, wfc1, 256, 4, GeluEpi{hidden, fc1b});
  // fc2 + residual: (100352,1024) @ (256,1024)^T, += into d_out — NT=1
  gemm256<<<392, 512, 131072, stream>>>(hidden, wfc2, 1024, 1, Fc2Epi{out, fc2b});
}

// Round 7
// 654.021 us; speedup vs baseline: 1.0862x; 1.0862x over previous
//
#include <hip/hip_runtime.h>

// ---------------------------------------------------------------------------
// Swin block, MI355X bf16-MFMA implementation.
// Shapes: B=32, H=W=56, DIM=256, WS=7, SHIFT=3, NH=8, HD=32, N=49, nW=64,
// Bw=2048, tokens T=100352.
// R1: attn_proj: comb bias table + LDS XOR-swizzles (landed)
// R2: gemm_bt 128²: dbuf prefetch + XCD-chunked grid (landed: 678 µs)
// R3/R5/R6: three pipeline/structure variants (counted vmcnt x2, 256² 8-wave)
//     all NULL/regressed -> schedule is not the lever at this occupancy.
// R4: mlp_fused (REGRESSED; reverted)
// R7: occupancy push on the R2 structure: unified VGPR+AGPR file charges
//     80+64(acc AGPRs)=144 regs/lane -> only 3 waves/SIMD. Force 4 waves/EU
//     via __launch_bounds__(256,4) + hoisted load pointers + HW bf16 cvt
//     (epilogue VALU diet). 4 blocks/CU of TLP is what actually hides the
//     stage latency (m114 implicit overlap).
// ---------------------------------------------------------------------------

typedef float f4 __attribute__((ext_vector_type(4)));
typedef __bf16 b8 __attribute__((ext_vector_type(8)));

#define DEV static __device__ __forceinline__

DEV ushort f2bf(float f) {
  union { __bf16 b; ushort u; } c; c.b = (__bf16)f;   // HW v_cvt, RNE
  return c.u;
}
DEV __bf16 bfb(ushort u) { union { ushort u; __bf16 b; } c; c.u = u; return c.b; }
DEV b8 zero_b8() {
  b8 z;
#pragma unroll
  for (int i = 0; i < 8; ++i) z[i] = (__bf16)0.f;
  return z;
}
DEV void load_lds16(const void* g, void* l) {
  // lane i's 16B land at ldsbase + i*16 (wave-uniform base) [m97/m104]
  __builtin_amdgcn_global_load_lds(
      (const __attribute__((address_space(1))) unsigned int*)g,
      (__attribute__((address_space(3))) unsigned int*)l, 16, 0, 0);
}
DEV int reg3(int t) { return t < 49 ? 0 : (t < 53 ? 1 : 2); }  // shift-mask region row/col id

// ---------------------------------------------------------------------------
// weights fp32 -> bf16
__global__ __launch_bounds__(256) void cast_w(const float* a, ushort* oa, int na,
                                              const float* b, ushort* ob, int nb,
                                              const float* c, ushort* oc, int nc,
                                              const float* d, ushort* od, int nd) {
  int total = na + nb + nc + nd;
  for (int i = blockIdx.x * 256 + threadIdx.x; i < total; i += gridDim.x * 256) {
    int j = i;
    if (j < na) { oa[j] = f2bf(a[j]); continue; }
    j -= na;
    if (j < nb) { ob[j] = f2bf(b[j]); continue; }
    j -= nb;
    if (j < nc) { oc[j] = f2bf(c[j]); continue; }
    j -= nc;
    od[j] = f2bf(d[j]);
  }
}

// ---------------------------------------------------------------------------
// comb[type][h][i][j]: rel-pos bias + shift mask + pad (-1e30), fp32.
// type = (wh==7)*2 + (ww==7) — only 4 distinct window mask patterns exist.
__global__ __launch_bounds__(256) void build_bias(const float* __restrict__ rel_table,
                                                  float* __restrict__ comb) {
  const int idx = blockIdx.x * 256 + threadIdx.x;  // 4*8*64*64 = 131072
  if (idx >= 4 * 8 * 64 * 64) return;
  const int j = idx & 63, i = (idx >> 6) & 63, h = (idx >> 12) & 7, ty = idx >> 15;
  float v;
  if (i < 49 && j < 49) {
    const int iy = i / 7, ix = i - iy * 7, jy = j / 7, jx = j - jy * 7;
    const int ridx = (iy - jy + 6) * 13 + (ix - jx + 6);
    v = rel_table[ridx * 8 + h];
    const int wh = (ty & 2) ? 7 : 0, ww = (ty & 1) ? 7 : 0;
    const int irg = reg3(wh * 7 + iy) * 3 + reg3(ww * 7 + ix);
    const int jrg = reg3(wh * 7 + jy) * 3 + reg3(ww * 7 + jx);
    if (irg != jrg) v -= 100.f;
  } else {
    v = -1e30f;  // padding: exp(-inf) = 0 for j>=49; rows i>=49 harmless
  }
  comb[idx] = v;
}

// ---------------------------------------------------------------------------
// LayerNorm over 256 ch, one wave per token; optional (-3,-3) cyclic shift +
// window partition on the output index. out: bf16 (token, 256) row-major.
__global__ __launch_bounds__(256) void ln_shift(const float* __restrict__ x,
                                                const float* __restrict__ g,
                                                const float* __restrict__ bta,
                                                ushort* __restrict__ out, int shifted) {
  const int wid = threadIdx.x >> 6, lane = threadIdx.x & 63;
  const int t = blockIdx.x * 4 + wid;           // output token (windowed order if shifted)
  int src;
  if (shifted) {
    int win = t / 49, n = t - win * 49;
    int bb = win >> 6, wh = (win >> 3) & 7, ww = win & 7;
    int wy = n / 7, wx = n - wy * 7;
    int r = wh * 7 + wy + 3; if (r >= 56) r -= 56;
    int c = ww * 7 + wx + 3; if (c >= 56) c -= 56;
    src = bb * 3136 + r * 56 + c;
  } else {
    src = t;
  }
  const float4 v = *(const float4*)(x + (size_t)src * 256 + lane * 4);
  float s  = v.x + v.y + v.z + v.w;
  float s2 = v.x * v.x + v.y * v.y + v.z * v.z + v.w * v.w;
#pragma unroll
  for (int m = 32; m; m >>= 1) { s += __shfl_xor(s, m); s2 += __shfl_xor(s2, m); }
  const float mean = s * (1.f / 256.f);
  const float var  = s2 * (1.f / 256.f) - mean * mean;
  const float rs   = rsqrtf(var + 1e-5f);
  const float4 gv = *(const float4*)(g + lane * 4);
  const float4 bv = *(const float4*)(bta + lane * 4);
  ushort4 o;
  o.x = f2bf((v.x - mean) * rs * gv.x + bv.x);
  o.y = f2bf((v.y - mean) * rs * gv.y + bv.y);
  o.z = f2bf((v.z - mean) * rs * gv.z + bv.z);
  o.w = f2bf((v.w - mean) * rs * gv.w + bv.w);
  *(ushort4*)(out + (size_t)t * 256 + lane * 4) = o;
}

// ---------------------------------------------------------------------------
// Generic bf16 GEMM: C[M,N] = A[M,K] @ B[N,K]^T, 128x128 tile, BK=32,
// 256 thr (2x2 waves, 64x64 each), global_load_lds width-16 staging (m97),
// double-buffered: tile t+1 staged while tile t computes.
// __launch_bounds__(256,4): cap unified regs at 128/lane (acc=64 AGPR +
// <=64 arch) -> 4 waves/SIMD -> 4 blocks/CU resident (was 3) for TLP.
// 1D grid, XCD-chunked swizzle: lin%8 = XCD, each XCD gets a contiguous
// chunk of M-stripes with ALL their N-tiles -> A-stripe reuse is same-L2.
template <class Epi>
__global__ __launch_bounds__(256, 4) void gemm_bt(const ushort* __restrict__ A,
                                                  const ushort* __restrict__ B,
                                                  int K, int NT, Epi epi) {
  __shared__ ushort lsA[2][128 * 32];
  __shared__ ushort lsB[2][128 * 32];
  const int tid = threadIdx.x;
  const int lane = tid & 63, wid = tid >> 6;
  const int quad = lane >> 4, l16 = lane & 15;
  const int wm = wid >> 1, wn = wid & 1;
  // XCD-chunked bijective remap (nwg = 784*NT, divisible by 8)
  const int lin = blockIdx.x;
  const int xcd = lin & 7, j = lin >> 3;
  const int mt = xcd * 98 + j / NT;            // 98 = 784/8 stripes per XCD
  const int nt_ = j % NT;
  const long rowA0 = (long)mt * 128;
  const long colB0 = (long)nt_ * 128;
  f4 acc[4][4];
#pragma unroll
  for (int i = 0; i < 4; ++i)
#pragma unroll
    for (int jj = 0; jj < 4; ++jj) { acc[i][jj][0] = 0.f; acc[i][jj][1] = 0.f; acc[i][jj][2] = 0.f; acc[i][jj][3] = 0.f; }
  const int lrow = lane >> 2;
  const int lk = ((lane & 3) ^ ((lane >> 3) & 3)) * 8;   // swizzled global k-chunk
  const int rsw = (quad ^ ((l16 >> 1) & 3)) * 8;         // swizzled read slot
  // hoisted per-block load pointers (loop adds only k offset)
  const int seg0 = wid * 2, seg1 = wid * 2 + 1;
  const ushort* pa0 = A + (rowA0 + seg0 * 16 + lrow) * (long)K + lk;
  const ushort* pa1 = A + (rowA0 + seg1 * 16 + lrow) * (long)K + lk;
  const ushort* pb0 = B + (colB0 + seg0 * 16 + lrow) * (long)K + lk;
  const ushort* pb1 = B + (colB0 + seg1 * 16 + lrow) * (long)K + lk;

  const int nsteps = K >> 5;
  // prologue: stage tile 0
  load_lds16(pa0, &lsA[0][seg0 * 512]);
  load_lds16(pa1, &lsA[0][seg1 * 512]);
  load_lds16(pb0, &lsB[0][seg0 * 512]);
  load_lds16(pb1, &lsB[0][seg1 * 512]);
  __syncthreads();  // drains own vmcnt -> tile 0 resident

  for (int t = 0; t < nsteps; ++t) {
    const int cur = t & 1;
    if (t + 1 < nsteps) {
      const int k1 = (t + 1) << 5;
      load_lds16(pa0 + k1, &lsA[cur ^ 1][seg0 * 512]);
      load_lds16(pa1 + k1, &lsA[cur ^ 1][seg1 * 512]);
      load_lds16(pb0 + k1, &lsB[cur ^ 1][seg0 * 512]);
      load_lds16(pb1 + k1, &lsB[cur ^ 1][seg1 * 512]);
    }
    b8 af[4], bfr[4];
#pragma unroll
    for (int ti = 0; ti < 4; ++ti)
      af[ti] = *(const b8*)&lsA[cur][(wm * 64 + ti * 16 + l16) * 32 + rsw];
#pragma unroll
    for (int tj = 0; tj < 4; ++tj)
      bfr[tj] = *(const b8*)&lsB[cur][(wn * 64 + tj * 16 + l16) * 32 + rsw];
#pragma unroll
    for (int ti = 0; ti < 4; ++ti)
#pragma unroll
      for (int tj = 0; tj < 4; ++tj)
        acc[ti][tj] = __builtin_amdgcn_mfma_f32_16x16x32_bf16(af[ti], bfr[tj], acc[ti][tj], 0, 0, 0);
    __syncthreads();  // drains prefetch vmcnt + all waves' ds_reads of cur
  }
  // C/D layout: row = quad*4+reg, col = lane&15 [m89/m91]
#pragma unroll
  for (int ti = 0; ti < 4; ++ti)
#pragma unroll
    for (int tj = 0; tj < 4; ++tj)
#pragma unroll
      for (int r = 0; r < 4; ++r)
        epi((int)(rowA0 + wm * 64 + ti * 16 + quad * 4 + r),
            (int)(colB0 + wn * 64 + tj * 16 + l16), acc[ti][tj][r]);
}

struct QkvEpi {
  ushort* out; const float* bias;
  __device__ void operator()(int r, int c, float v) const {
    v += bias[c];
    if (c < 256) v *= 0.17677669529663687f;  // HD^-0.5, pre-scale q
    out[(size_t)r * 768 + c] = f2bf(v);
  }
};
struct GeluEpi {
  ushort* out; const float* bias;
  __device__ void operator()(int r, int c, float v) const {
    v += bias[c];
    v = 0.5f * v * (1.f + erff(v * 0.70710678118654752f));  // exact gelu
    out[(size_t)r * 1024 + c] = f2bf(v);
  }
};
struct Fc2Epi {
  float* out; const float* bias;
  __device__ void operator()(int r, int c, float v) const {
    size_t i = (size_t)r * 256 + c;
    out[i] = out[i] + v + bias[c];  // += y onto x_after already in d_out
  }
};

// ---------------------------------------------------------------------------
// Attention + proj + residual + LN2, one block per window (512 thr), one
// wave/head. qkv rows: [q(256, pre-scaled) | k(256) | v(256)] bf16.
// Writes x_after (fp32, d_out) and LN2(x_after) (bf16, fc1's A) directly.
__global__ __launch_bounds__(512) void attn_proj(const ushort* __restrict__ qkv,
                                                 const float* __restrict__ comb,
                                                 const ushort* __restrict__ projw,
                                                 const float* __restrict__ projb,
                                                 const float* __restrict__ x_in,
                                                 const float* __restrict__ n2g,
                                                 const float* __restrict__ n2b,
                                                 float* __restrict__ x_out,
                                                 ushort* __restrict__ xw2) {
  __shared__ ushort sbuf[32768];  // 64KB: P (8 x 64x64) ; O staging ; fp32 x_after
  const int win = blockIdx.x;
  const int b = win >> 6, wh = (win >> 3) & 7, ww = win & 7;
  const int tid = threadIdx.x, lane = tid & 63, h = tid >> 6;
  const int quad = lane >> 4, l16 = lane & 15;
  const size_t wbase = (size_t)win * 49 * 768;

  // ---- Phase 1: S = (q*scale) @ k^T, padded to 64x64, K=32 (one MFMA/tile)
  b8 af[4], bfr[4];
#pragma unroll
  for (int ti = 0; ti < 4; ++ti) {
    const int tok = ti * 16 + l16;
    af[ti] = (tok < 49) ? *(const b8*)(qkv + wbase + (size_t)tok * 768 + h * 32 + quad * 8)
                        : zero_b8();
  }
#pragma unroll
  for (int tj = 0; tj < 4; ++tj) {
    const int key = tj * 16 + l16;
    bfr[tj] = (key < 49) ? *(const b8*)(qkv + wbase + (size_t)key * 768 + 256 + h * 32 + quad * 8)
                         : zero_b8();
  }
  f4 S[4][4];
#pragma unroll
  for (int ti = 0; ti < 4; ++ti)
#pragma unroll
    for (int tj = 0; tj < 4; ++tj) {
      S[ti][tj][0] = 0.f; S[ti][tj][1] = 0.f; S[ti][tj][2] = 0.f; S[ti][tj][3] = 0.f;
      S[ti][tj] = __builtin_amdgcn_mfma_f32_16x16x32_bf16(af[ti], bfr[tj], S[ti][tj], 0, 0, 0);
    }

  // ---- Phase 2: + precombined bias/mask table (coalesced L2 reads), row
  // softmax, P -> LDS bf16 with 16B-chunk XOR swizzle (chunk ^= row&7).
  ushort* P = sbuf + h * 4096;  // this head's 64x64
  const float* cmb = comb + ((((wh == 7) ? 2 : 0) + ((ww == 7) ? 1 : 0)) * 8 + h) * 4096;
#pragma unroll
  for (int ti = 0; ti < 4; ++ti) {
#pragma unroll
    for (int r = 0; r < 4; ++r) {
      const int i = ti * 16 + quad * 4 + r;
      const float* crow = cmb + i * 64 + l16;
      float sv[4];
#pragma unroll
      for (int tj = 0; tj < 4; ++tj) sv[tj] = S[ti][tj][r] + crow[tj * 16];
      float m = fmaxf(fmaxf(sv[0], sv[1]), fmaxf(sv[2], sv[3]));
#pragma unroll
      for (int d = 1; d < 16; d <<= 1) m = fmaxf(m, __shfl_xor(m, d));
      float sum = 0.f;
#pragma unroll
      for (int tj = 0; tj < 4; ++tj) { sv[tj] = __expf(sv[tj] - m); sum += sv[tj]; }
#pragma unroll
      for (int d = 1; d < 16; d <<= 1) sum += __shfl_xor(sum, d);
      const float inv = 1.f / sum;
      const int swz = i & 7, off = l16 & 7, cb = l16 >> 3;
#pragma unroll
      for (int tj = 0; tj < 4; ++tj) {
        const int cc = tj * 2 + cb;
        P[i * 64 + (((cc ^ swz) << 3) | off)] = f2bf(sv[tj] * inv);
      }
    }
  }

  // ---- Phase 3: O = P @ V (K=64 keys, 2 MFMAs per 16x16 out tile)
  f4 O[4][2];
#pragma unroll
  for (int ti = 0; ti < 4; ++ti)
#pragma unroll
    for (int tn = 0; tn < 2; ++tn) { O[ti][tn][0] = 0.f; O[ti][tn][1] = 0.f; O[ti][tn][2] = 0.f; O[ti][tn][3] = 0.f; }
#pragma unroll
  for (int kt = 0; kt < 2; ++kt) {
    b8 vb[2];
#pragma unroll
    for (int tn = 0; tn < 2; ++tn)
#pragma unroll
      for (int j = 0; j < 8; ++j) {
        const int key = kt * 32 + quad * 8 + j;  // B-frag: b[j]=V[k=quad*8+j][n=lane&15]
        vb[tn][j] = (key < 49)
            ? bfb(qkv[wbase + (size_t)key * 768 + 512 + h * 32 + tn * 16 + l16])
            : (__bf16)0.f;
      }
#pragma unroll
    for (int ti = 0; ti < 4; ++ti) {
      const int row = ti * 16 + l16;
      const b8 pa = *(const b8*)(P + row * 64 + (((kt * 4 + quad) ^ (row & 7)) << 3));
#pragma unroll
      for (int tn = 0; tn < 2; ++tn)
        O[ti][tn] = __builtin_amdgcn_mfma_f32_16x16x32_bf16(pa, vb[tn], O[ti][tn], 0, 0, 0);
    }
  }

  // ---- Phase 4: stage O (64 x 256 bf16) in LDS, XOR-swizzled (aliases P)
  __syncthreads();
  ushort* ob = sbuf;
#pragma unroll
  for (int ti = 0; ti < 4; ++ti)
#pragma unroll
    for (int tn = 0; tn < 2; ++tn)
#pragma unroll
      for (int r = 0; r < 4; ++r) {
        const int tok = ti * 16 + quad * 4 + r;
        const int cc = h * 4 + tn * 2 + (l16 >> 3);
        ob[tok * 256 + (((cc ^ (tok & 7)) << 3) | (l16 & 7))] = f2bf(O[ti][tn][r]);
      }
  __syncthreads();

  // ---- Phase 5: proj: (64x256) @ projw(256,256)^T; wave h owns 32 out cols
  f4 C[4][2];
#pragma unroll
  for (int ti = 0; ti < 4; ++ti)
#pragma unroll
    for (int tn = 0; tn < 2; ++tn) { C[ti][tn][0] = 0.f; C[ti][tn][1] = 0.f; C[ti][tn][2] = 0.f; C[ti][tn][3] = 0.f; }
  for (int k0 = 0; k0 < 256; k0 += 32) {
    b8 bw[2];
#pragma unroll
    for (int tn = 0; tn < 2; ++tn)
      bw[tn] = *(const b8*)(projw + (size_t)(h * 32 + tn * 16 + l16) * 256 + k0 + quad * 8);
#pragma unroll
    for (int ti = 0; ti < 4; ++ti) {
      const int row = ti * 16 + l16;
      const b8 pa = *(const b8*)(ob + row * 256 + ((((k0 >> 3) + quad) ^ (row & 7)) << 3));
#pragma unroll
      for (int tn = 0; tn < 2; ++tn)
        C[ti][tn] = __builtin_amdgcn_mfma_f32_16x16x32_bf16(pa, bw[tn], C[ti][tn], 0, 0, 0);
    }
  }

  // ---- Phase 6: stage proj output (64x256 fp32, 64KB) in LDS, float4-chunk
  // XOR swizzle (chunk ^= tok&7) to spread write banks.
  __syncthreads();  // all waves done reading ob
  float* fbuf = (float*)sbuf;
#pragma unroll
  for (int ti = 0; ti < 4; ++ti)
#pragma unroll
    for (int r = 0; r < 4; ++r) {
      const int tok = ti * 16 + quad * 4 + r;
      const int swz = tok & 7;
#pragma unroll
      for (int tn = 0; tn < 2; ++tn) {
        const int c4 = h * 8 + tn * 4 + (l16 >> 2);
        fbuf[tok * 256 + (((c4 ^ swz) << 2) | (l16 & 3))] = C[ti][tn][r];
      }
    }
  __syncthreads();

  // ---- Phase 7: per-token: x_after = proj + projb + shortcut (inverse
  // shift), store fp32; fused LN2 -> bf16 xw2 (raster token order).
  for (int t = h; t < 49; t += 8) {
    const int wy = t / 7, wx = t - wy * 7;
    int rr = wh * 7 + wy + 3; if (rr >= 56) rr -= 56;
    int cc = ww * 7 + wx + 3; if (cc >= 56) cc -= 56;
    const size_t base = ((size_t)b * 3136 + rr * 56 + cc) * 256;
    // swizzled read: location chunk lane^(t&7) holds column chunk `lane`
    float4 v = *(float4*)&fbuf[t * 256 + ((lane ^ (t & 7)) << 2)];
    const float4 pb = *(const float4*)(projb + lane * 4);
    const float4 xr = *(const float4*)(x_in + base + lane * 4);
    v.x += pb.x + xr.x; v.y += pb.y + xr.y; v.z += pb.z + xr.z; v.w += pb.w + xr.w;
    *(float4*)(x_out + base + lane * 4) = v;
    float s  = v.x + v.y + v.z + v.w;
    float s2 = v.x * v.x + v.y * v.y + v.z * v.z + v.w * v.w;
#pragma unroll
    for (int m = 32; m; m >>= 1) { s += __shfl_xor(s, m); s2 += __shfl_xor(s2, m); }
    const float mean = s * (1.f / 256.f);
    const float var  = s2 * (1.f / 256.f) - mean * mean;
    const float rs   = rsqrtf(var + 1e-5f);
    const float4 gv = *(const float4*)(n2g + lane * 4);
    const float4 bv = *(const float4*)(n2b + lane * 4);
    ushort4 o;
    o.x = f2bf((v.x - mean) * rs * gv.x + bv.x);
    o.y = f2bf((v.y - mean) * rs * gv.y + bv.y);
    o.z = f2bf((v.z - mean) * rs * gv.z + bv.z);
    o.w = f2bf((v.w - mean) * rs * gv.w + bv.w);
    *(ushort4*)(xw2 + base + lane * 4) = o;
  }
}

// ---------------------------------------------------------------------------
extern "C" void kernel_launch(void* const* d_in, const int* in_sizes, int n_in,
                              void* d_out, int out_size, void* d_ws, size_t ws_size,
                              hipStream_t stream) {
  const float* x     = (const float*)d_in[0];
  const float* n1g   = (const float*)d_in[1];
  const float* n1b   = (const float*)d_in[2];
  const float* qkvw  = (const float*)d_in[3];
  const float* qkvb  = (const float*)d_in[4];
  const float* relt  = (const float*)d_in[5];
  const float* projw = (const float*)d_in[6];
  const float* projb = (const float*)d_in[7];
  const float* n2g   = (const float*)d_in[8];
  const float* n2b   = (const float*)d_in[9];
  const float* fc1w  = (const float*)d_in[10];
  const float* fc1b  = (const float*)d_in[11];
  const float* fc2w  = (const float*)d_in[12];
  const float* fc2b  = (const float*)d_in[13];
  float* out = (float*)d_out;
  char* ws = (char*)d_ws;

  // ws layout:
  //   [0, 51.4MB)        xw: LN1 windowed bf16 A; reused as LN2 output (xw2)
  //   [51.4, 256.9MB)    qkv bf16 (154.1MB); reused as fc1 hidden (205.5MB)
  //   [205.5, 206.0MB)   comb bias/mask table (512KB) — dead space until fc1
  //                      overwrites it (attn_proj has finished by then)
  //   [256.9, 258.5MB)   bf16 weights
  ushort* xw     = (ushort*)ws;
  ushort* qkv    = (ushort*)(ws + 51380224);
  ushort* hidden = qkv;
  float*  comb   = (float*)(ws + 205520896);   // after qkv's 154,140,672 bytes
  ushort* wqkv   = (ushort*)(ws + 51380224 + 205520896);
  ushort* wproj  = wqkv + 196608;
  ushort* wfc1   = wproj + 65536;
  ushort* wfc2   = wfc1 + 262144;

  cast_w<<<768, 256, 0, stream>>>(qkvw, wqkv, 196608, projw, wproj, 65536,
                                  fc1w, wfc1, 262144, fc2w, wfc2, 262144);
  build_bias<<<512, 256, 0, stream>>>(relt, comb);
  // LN1 + shift + window partition -> bf16
  ln_shift<<<25088, 256, 0, stream>>>(x, n1g, n1b, xw, 1);
  // qkv: (100352,256) @ (768,256)^T — 1D grid, XCD-chunked, NT=6
  gemm_bt<<<4704, 256, 0, stream>>>(xw, wqkv, 256, 6, QkvEpi{qkv, qkvb});
  // attention + proj + residual + inverse shift + LN2 -> d_out, xw (bf16)
  attn_proj<<<2048, 512, 0, stream>>>(qkv, comb, wproj, projb, x, n2g, n2b, out, xw);
  // fc1 + gelu: (100352,256) @ (1024,256)^T — NT=8
  gemm_bt<<<6272, 256, 0, stream>>>(xw, wfc1, 256, 8, GeluEpi{hidden, fc1b});
  // fc2 + residual: (100352,1024) @ (256,1024)^T, += into d_out — NT=2
  gemm_bt<<<1568, 256, 0, stream>>>(hidden, wfc2, 1024, 2, Fc2Epi{out, fc2b});
}